// Round 7
// baseline (217.296 us; speedup 1.0000x reference)
//
#include <hip/hip_runtime.h>

#define NH 32
#define HD 128
#define PBS 16
#define HIDDEN (NH * HD)   // 4096
#define QKVN (3 * HIDDEN)  // 12288
#define NSPLIT 8

// out[b][n] = dot(x[b,:K], W[n,:K]) + bias[n], B=8 fixed.
// NR=4 rows per wave: x (L1) loads amortized over 4 weight rows.
__global__ __launch_bounds__(256) void gemv4r(const float* __restrict__ x,
                                              const float* __restrict__ W,
                                              const float* __restrict__ bias,
                                              float* __restrict__ out,
                                              int N, int K) {
    const int lane = threadIdx.x & 63;
    const int wv   = (blockIdx.x * blockDim.x + threadIdx.x) >> 6;
    const int n0   = wv * 4;
    if (n0 >= N) return;
    const float* w0 = W + (size_t)n0 * K;

    float acc[4][8];
#pragma unroll
    for (int r = 0; r < 4; ++r)
#pragma unroll
        for (int b = 0; b < 8; ++b) acc[r][b] = 0.f;

#pragma unroll 2
    for (int k0 = lane * 4; k0 < K; k0 += 256) {
        float4 w4[4];
#pragma unroll
        for (int r = 0; r < 4; ++r)
            w4[r] = *reinterpret_cast<const float4*>(w0 + (size_t)r * K + k0);
#pragma unroll
        for (int b = 0; b < 8; ++b) {
            const float4 x4 = *reinterpret_cast<const float4*>(x + (size_t)b * K + k0);
#pragma unroll
            for (int r = 0; r < 4; ++r)
                acc[r][b] += w4[r].x * x4.x + w4[r].y * x4.y +
                             w4[r].z * x4.z + w4[r].w * x4.w;
        }
    }
#pragma unroll
    for (int r = 0; r < 4; ++r)
#pragma unroll
        for (int b = 0; b < 8; ++b)
#pragma unroll
            for (int off = 32; off > 0; off >>= 1)
                acc[r][b] += __shfl_xor(acc[r][b], off, 64);
    if (lane == 0) {
#pragma unroll
        for (int r = 0; r < 4; ++r) {
            const float bv = bias ? bias[n0 + r] : 0.f;
#pragma unroll
            for (int b = 0; b < 8; ++b)
                out[(size_t)b * N + n0 + r] = acc[r][b] + bv;
        }
    }
}

// In-place RoPE on q and k halves of qkv ws. One thread per (part,b,h,d<64).
__global__ __launch_bounds__(256) void rope_k(float* __restrict__ qkv,
                                              const float* __restrict__ cosb,
                                              const float* __restrict__ sinb,
                                              int B) {
    const int tid = blockIdx.x * blockDim.x + threadIdx.x;
    const int total = 2 * B * NH * (HD / 2);
    if (tid >= total) return;
    const int d = tid % (HD / 2);
    const int h = (tid / (HD / 2)) % NH;
    const int b = (tid / (HD / 2) / NH) % B;
    const int part = tid / (HD / 2) / NH / B;  // 0=q, 1=k
    const float c = cosb[b * (HD / 2) + d];
    const float s = sinb[b * (HD / 2) + d];
    float* p = qkv + (size_t)b * QKVN + part * HIDDEN + h * HD + d;
    const float x1 = p[0];
    const float x2 = p[HD / 2];
    p[0]      = x1 * c - x2 * s;
    p[HD / 2] = x1 * s + x2 * c;
}

// Flash-style partial: one block per (b,h,split). 256 threads = 4 waves.
// Lane layout: lane = t16*4 + qi. A wave handles one PAGE (16 tokens) per
// iteration: token t16, quarter qi covers dims {u*16+qi*4 .. +3, u=0..7}.
// 8 independent float4 loads per page, 2-step score reduce (xor 1,2).
__global__ __launch_bounds__(256) void attn_part(const float* __restrict__ qkv,
                                                 const float* __restrict__ k_cache,
                                                 const float* __restrict__ v_cache,
                                                 const int* __restrict__ block_tables,
                                                 const int* __restrict__ slots,
                                                 const int* __restrict__ lengths,
                                                 float* __restrict__ part_o,
                                                 float* __restrict__ part_ml,
                                                 int S, int max_blocks) {
    const int split = blockIdx.x % NSPLIT;
    const int bh    = blockIdx.x / NSPLIT;
    const int b     = bh >> 5;
    const int h     = bh & 31;
    const int SP    = S / NSPLIT;       // 256
    const int base  = split * SP;
    const int NPG   = SP / PBS;         // 16 pages

    extern __shared__ float smem[];
    float* sc    = smem;                       // SP floats
    int*   bt    = (int*)(smem + SP);          // NPG ints
    float* red   = smem + SP + NPG;            // 16 floats
    float* stage = red + 16;                   // nw*HD floats

    const int tid  = threadIdx.x;
    const int lane = tid & 63;
    const int wid  = tid >> 6;
    const int nw   = blockDim.x >> 6;   // 4
    const int t16  = lane >> 2;          // token in page, 0..15
    const int qi   = lane & 3;           // quarter, 0..3

    for (int i = tid; i < NPG; i += blockDim.x)
        bt[i] = block_tables[b * max_blocks + base / PBS + i];
    __syncthreads();

    const int slot_b = slots[b];
    const int len    = lengths[b];
    const float scale = 0.088388347648318447f;  // 1/sqrt(128)

    const float* qp   = qkv + (size_t)b * QKVN + h * HD;
    const float* newk = qp + HIDDEN;
    const float* newv = qp + 2 * HIDDEN;

    float4 qf[8];
#pragma unroll
    for (int u = 0; u < 8; ++u)
        qf[u] = *reinterpret_cast<const float4*>(qp + u * 16 + qi * 4);

    // ---- Pass A: scores. One page (16 tokens) per wave-iteration.
    for (int pg = wid; pg < NPG; pg += nw) {
        const int idx = bt[pg] * PBS + t16;
        const float* kp = (idx == slot_b) ? newk
                                          : (k_cache + (size_t)idx * HIDDEN + h * HD);
        float4 k4[8];
#pragma unroll
        for (int u = 0; u < 8; ++u)
            k4[u] = *reinterpret_cast<const float4*>(kp + u * 16 + qi * 4);
        float d = 0.f;
#pragma unroll
        for (int u = 0; u < 8; ++u)
            d += k4[u].x * qf[u].x + k4[u].y * qf[u].y +
                 k4[u].z * qf[u].z + k4[u].w * qf[u].w;
        d += __shfl_xor(d, 1, 64);
        d += __shfl_xor(d, 2, 64);
        if (qi == 0) {
            const int ploc = pg * PBS + t16;
            sc[ploc] = (base + ploc < len) ? d * scale : -1e30f;
        }
    }
    __syncthreads();

    // ---- Local softmax over SP in LDS.
    float m = -1e30f;
    for (int s = tid; s < SP; s += blockDim.x) m = fmaxf(m, sc[s]);
#pragma unroll
    for (int off = 32; off > 0; off >>= 1) m = fmaxf(m, __shfl_xor(m, off, 64));
    if (lane == 0) red[wid] = m;
    __syncthreads();
    float bm = red[0];
    for (int w = 1; w < nw; ++w) bm = fmaxf(bm, red[w]);
    __syncthreads();

    float lsum = 0.f;
    for (int s = tid; s < SP; s += blockDim.x) {
        const float e = __expf(sc[s] - bm);
        sc[s] = e;
        lsum += e;
    }
#pragma unroll
    for (int off = 32; off > 0; off >>= 1) lsum += __shfl_xor(lsum, off, 64);
    if (lane == 0) red[wid] = lsum;
    __syncthreads();
    float tot = 0.f;
    for (int w = 0; w < nw; ++w) tot += red[w];

    // ---- Pass B: o[d] += p[t] * V[t][d]; lane accumulates its 32 dims.
    float4 acc[8];
#pragma unroll
    for (int u = 0; u < 8; ++u) acc[u] = make_float4(0.f, 0.f, 0.f, 0.f);
    for (int pg = wid; pg < NPG; pg += nw) {
        const int idx = bt[pg] * PBS + t16;
        const float* vp = (idx == slot_b) ? newv
                                          : (v_cache + (size_t)idx * HIDDEN + h * HD);
        float4 v4[8];
#pragma unroll
        for (int u = 0; u < 8; ++u)
            v4[u] = *reinterpret_cast<const float4*>(vp + u * 16 + qi * 4);
        const float pt = sc[pg * PBS + t16];
#pragma unroll
        for (int u = 0; u < 8; ++u) {
            acc[u].x += pt * v4[u].x;
            acc[u].y += pt * v4[u].y;
            acc[u].z += pt * v4[u].z;
            acc[u].w += pt * v4[u].w;
        }
    }
    // reduce across the 16 token-lanes (same qi): lane bits 2..5
#pragma unroll
    for (int u = 0; u < 8; ++u) {
#pragma unroll
        for (int off = 4; off <= 32; off <<= 1) {
            acc[u].x += __shfl_xor(acc[u].x, off, 64);
            acc[u].y += __shfl_xor(acc[u].y, off, 64);
            acc[u].z += __shfl_xor(acc[u].z, off, 64);
            acc[u].w += __shfl_xor(acc[u].w, off, 64);
        }
    }
    if (t16 == 0) {
#pragma unroll
        for (int u = 0; u < 8; ++u)
            *reinterpret_cast<float4*>(&stage[wid * HD + u * 16 + qi * 4]) = acc[u];
    }
    __syncthreads();
    if (wid == 0) {
        float t0 = 0.f, t1 = 0.f;
        for (int w = 0; w < nw; ++w) {
            t0 += stage[w * HD + lane * 2];
            t1 += stage[w * HD + lane * 2 + 1];
        }
        float* po = part_o + ((size_t)bh * NSPLIT + split) * HD;
        po[lane * 2]     = t0;
        po[lane * 2 + 1] = t1;
        if (lane == 0) {
            part_ml[((size_t)bh * NSPLIT + split) * 2]     = bm;
            part_ml[((size_t)bh * NSPLIT + split) * 2 + 1] = tot;
        }
    }
}

// Combine NSPLIT partials per (b,h). One block per bh, HD threads.
__global__ __launch_bounds__(HD) void attn_reduce(const float* __restrict__ part_o,
                                                  const float* __restrict__ part_ml,
                                                  float* __restrict__ attn_out) {
    const int bh = blockIdx.x;
    const int d  = threadIdx.x;
    float M = -1e30f;
#pragma unroll
    for (int i = 0; i < NSPLIT; ++i)
        M = fmaxf(M, part_ml[((size_t)bh * NSPLIT + i) * 2]);
    float L = 0.f, o = 0.f;
#pragma unroll
    for (int i = 0; i < NSPLIT; ++i) {
        const float mi = part_ml[((size_t)bh * NSPLIT + i) * 2];
        const float li = part_ml[((size_t)bh * NSPLIT + i) * 2 + 1];
        const float w  = __expf(mi - M);
        L += li * w;
        o += part_o[((size_t)bh * NSPLIT + i) * HD + d] * w;
    }
    attn_out[(size_t)bh * HD + d] = o / L;
}

extern "C" void kernel_launch(void* const* d_in, const int* in_sizes, int n_in,
                              void* d_out, int out_size, void* d_ws, size_t ws_size,
                              hipStream_t stream) {
    const float* hidden  = (const float*)d_in[0];
    const float* cosb    = (const float*)d_in[1];
    const float* sinb    = (const float*)d_in[2];
    const float* w_qkv   = (const float*)d_in[3];
    const float* b_qkv   = (const float*)d_in[4];
    const float* w_o     = (const float*)d_in[5];
    const float* k_cache = (const float*)d_in[6];
    const float* v_cache = (const float*)d_in[7];
    const int*   btab    = (const int*)d_in[8];
    const int*   slots   = (const int*)d_in[9];
    const int*   lens    = (const int*)d_in[10];

    const int B = in_sizes[0] / HIDDEN;      // 8
    const int max_blocks = in_sizes[8] / B;  // 128
    const int S = max_blocks * PBS;          // 2048

    float* qkv     = (float*)d_ws;                        // [B][QKVN]
    float* attn    = qkv + (size_t)B * QKVN;              // [B][HIDDEN]
    float* part_o  = attn + (size_t)B * HIDDEN;           // [B*NH*NSPLIT][HD]
    float* part_ml = part_o + (size_t)B * NH * NSPLIT * HD;  // [B*NH*NSPLIT][2]
    float* out     = (float*)d_out;

    // 1) qkv = hidden @ w_qkv^T + b_qkv   (4 rows per wave)
    gemv4r<<<QKVN / 16, 256, 0, stream>>>(hidden, w_qkv, b_qkv, qkv, QKVN, HIDDEN);

    // 2) RoPE on q and k
    {
        const int total = 2 * B * NH * (HD / 2);
        rope_k<<<(total + 255) / 256, 256, 0, stream>>>(qkv, cosb, sinb, B);
    }

    // 3) paged attention partials + reduce
    {
        const int SP = S / NSPLIT;
        const size_t smem = (size_t)(SP + SP / PBS + 16 + 4 * HD) * sizeof(float);
        attn_part<<<B * NH * NSPLIT, 256, smem, stream>>>(qkv, k_cache, v_cache,
                                                          btab, slots, lens,
                                                          part_o, part_ml, S, max_blocks);
        attn_reduce<<<B * NH, HD, 0, stream>>>(part_o, part_ml, attn);
    }

    // 4) out = attn @ w_o^T
    gemv4r<<<HIDDEN / 16, 256, 0, stream>>>(attn, w_o, nullptr, out, HIDDEN, HIDDEN);
}

// Round 8
// 186.635 us; speedup vs baseline: 1.1643x; 1.1643x over previous
//
#include <hip/hip_runtime.h>

#define NH 32
#define HD 128
#define PBS 16
#define HIDDEN (NH * HD)   // 4096
#define QKVN (3 * HIDDEN)  // 12288
#define NSPLIT 8
#define KC 512             // k-chunk staged in LDS

// out[b][n] = dot(x[b,:K], W[n,:K]) + bias[n], B=8 fixed.
// Block = 256 thr = 4 waves; each wave owns NR rows; x staged in LDS per
// k-chunk (one x read per block, not per wave) to kill the L2 slice hotspot.
template <int NR>
__global__ __launch_bounds__(256) void gemv_lds(const float* __restrict__ x,
                                                const float* __restrict__ W,
                                                const float* __restrict__ bias,
                                                float* __restrict__ out,
                                                int N, int K) {
    __shared__ float xs[8][KC];
    const int tid  = threadIdx.x;
    const int lane = tid & 63;
    const int wid  = tid >> 6;
    const int n0   = blockIdx.x * (NR * 4) + wid * NR;
    const float* w0 = W + (size_t)n0 * K;

    float acc[NR][8];
#pragma unroll
    for (int r = 0; r < NR; ++r)
#pragma unroll
        for (int b = 0; b < 8; ++b) acc[r][b] = 0.f;

    for (int kc = 0; kc < K; kc += KC) {
        __syncthreads();  // previous chunk fully consumed
        // stage x[8][KC]: thread t covers batch t>>5, granules (t&31)+j*32
        {
            const int bq  = tid >> 5;
            const int t32 = tid & 31;
            const float* xb = x + (size_t)bq * K + kc;
#pragma unroll
            for (int j = 0; j < 4; ++j) {
                const int off = (t32 + j * 32) * 4;
                *reinterpret_cast<float4*>(&xs[bq][off]) =
                    *reinterpret_cast<const float4*>(xb + off);
            }
        }
        __syncthreads();
        // compute: lane covers k-pieces lane*4 and lane*4+256 within chunk
#pragma unroll
        for (int j = 0; j < 2; ++j) {
            const int kk = lane * 4 + j * 256;
            float4 w4[NR];
#pragma unroll
            for (int r = 0; r < NR; ++r)
                w4[r] = *reinterpret_cast<const float4*>(w0 + (size_t)r * K + kc + kk);
#pragma unroll
            for (int b = 0; b < 8; ++b) {
                const float4 x4 = *reinterpret_cast<const float4*>(&xs[b][kk]);
#pragma unroll
                for (int r = 0; r < NR; ++r)
                    acc[r][b] += w4[r].x * x4.x + w4[r].y * x4.y +
                                 w4[r].z * x4.z + w4[r].w * x4.w;
            }
        }
    }
#pragma unroll
    for (int r = 0; r < NR; ++r)
#pragma unroll
        for (int b = 0; b < 8; ++b)
#pragma unroll
            for (int off = 32; off > 0; off >>= 1)
                acc[r][b] += __shfl_xor(acc[r][b], off, 64);
    if (lane == 0) {
#pragma unroll
        for (int r = 0; r < NR; ++r) {
            const float bv = bias ? bias[n0 + r] : 0.f;
#pragma unroll
            for (int b = 0; b < 8; ++b)
                out[(size_t)b * N + n0 + r] = acc[r][b] + bv;
        }
    }
}

// In-place RoPE on q and k halves of qkv ws. One thread per (part,b,h,d<64).
__global__ __launch_bounds__(256) void rope_k(float* __restrict__ qkv,
                                              const float* __restrict__ cosb,
                                              const float* __restrict__ sinb,
                                              int B) {
    const int tid = blockIdx.x * blockDim.x + threadIdx.x;
    const int total = 2 * B * NH * (HD / 2);
    if (tid >= total) return;
    const int d = tid % (HD / 2);
    const int h = (tid / (HD / 2)) % NH;
    const int b = (tid / (HD / 2) / NH) % B;
    const int part = tid / (HD / 2) / NH / B;  // 0=q, 1=k
    const float c = cosb[b * (HD / 2) + d];
    const float s = sinb[b * (HD / 2) + d];
    float* p = qkv + (size_t)b * QKVN + part * HIDDEN + h * HD + d;
    const float x1 = p[0];
    const float x2 = p[HD / 2];
    p[0]      = x1 * c - x2 * s;
    p[HD / 2] = x1 * s + x2 * c;
}

// Flash-style partial: one block per (b,h,split). 256 threads = 4 waves.
// Half-wave per position, float4 loads, U=8 unroll (R6 layout — best known).
__global__ __launch_bounds__(256) void attn_part(const float* __restrict__ qkv,
                                                 const float* __restrict__ k_cache,
                                                 const float* __restrict__ v_cache,
                                                 const int* __restrict__ block_tables,
                                                 const int* __restrict__ slots,
                                                 const int* __restrict__ lengths,
                                                 float* __restrict__ part_o,
                                                 float* __restrict__ part_ml,
                                                 int S, int max_blocks) {
    const int split = blockIdx.x % NSPLIT;
    const int bh    = blockIdx.x / NSPLIT;
    const int b     = bh >> 5;
    const int h     = bh & 31;
    const int SP    = S / NSPLIT;       // 256
    const int base  = split * SP;

    extern __shared__ float smem[];
    float* sc    = smem;                       // SP floats
    int*   bt    = (int*)(smem + SP);          // SP/PBS ints
    float* red   = smem + SP + SP / PBS;       // 16 floats
    float* stage = red + 16;                   // nw*HD floats

    const int tid  = threadIdx.x;
    const int lane = tid & 63;
    const int wid  = tid >> 6;
    const int nw   = blockDim.x >> 6;   // 4
    const int half = lane >> 5;
    const int l32  = lane & 31;

    const int nbt = SP / PBS;  // 16
    for (int i = tid; i < nbt; i += blockDim.x)
        bt[i] = block_tables[b * max_blocks + base / PBS + i];
    __syncthreads();

    const int slot_b = slots[b];
    const int len    = lengths[b];
    const float scale = 0.088388347648318447f;  // 1/sqrt(128)

    const float* qp   = qkv + (size_t)b * QKVN + h * HD;
    const float* newk = qp + HIDDEN;
    const float* newv = qp + 2 * HIDDEN;
    const float4 q4 = *reinterpret_cast<const float4*>(qp + l32 * 4);

    // ---- Pass A: scores for local positions [0, SP).
    const int STEP = nw * 16;  // 64
    for (int s0 = wid * 16; s0 < SP; s0 += STEP) {
        float4 k4[8];
#pragma unroll
        for (int u = 0; u < 8; ++u) {
            const int p = s0 + u * 2 + half;
            const int idx = bt[p >> 4] * PBS + (p & (PBS - 1));
            const float* kp = (idx == slot_b) ? newk
                                              : (k_cache + (size_t)idx * HIDDEN + h * HD);
            k4[u] = *reinterpret_cast<const float4*>(kp + l32 * 4);
        }
#pragma unroll
        for (int u = 0; u < 8; ++u) {
            const int p = s0 + u * 2 + half;
            float d = k4[u].x * q4.x + k4[u].y * q4.y + k4[u].z * q4.z + k4[u].w * q4.w;
#pragma unroll
            for (int off = 16; off > 0; off >>= 1) d += __shfl_xor(d, off, 64);
            if (l32 == 0) sc[p] = (base + p < len) ? d * scale : -1e30f;
        }
    }
    __syncthreads();

    // ---- Local softmax over SP in LDS.
    float m = -1e30f;
    for (int s = tid; s < SP; s += blockDim.x) m = fmaxf(m, sc[s]);
#pragma unroll
    for (int off = 32; off > 0; off >>= 1) m = fmaxf(m, __shfl_xor(m, off, 64));
    if (lane == 0) red[wid] = m;
    __syncthreads();
    float bm = red[0];
    for (int w = 1; w < nw; ++w) bm = fmaxf(bm, red[w]);
    __syncthreads();

    float lsum = 0.f;
    for (int s = tid; s < SP; s += blockDim.x) {
        const float e = __expf(sc[s] - bm);
        sc[s] = e;
        lsum += e;
    }
#pragma unroll
    for (int off = 32; off > 0; off >>= 1) lsum += __shfl_xor(lsum, off, 64);
    if (lane == 0) red[wid] = lsum;
    __syncthreads();
    float tot = 0.f;
    for (int w = 0; w < nw; ++w) tot += red[w];

    // ---- Pass B: o[d] = sum_s e[s]*v[s][d] (unnormalized).
    float4 acc[8];
#pragma unroll
    for (int u = 0; u < 8; ++u) acc[u] = make_float4(0.f, 0.f, 0.f, 0.f);
    for (int s0 = wid * 16; s0 < SP; s0 += STEP) {
        float4 v4[8];
        float pr[8];
#pragma unroll
        for (int u = 0; u < 8; ++u) {
            const int p = s0 + u * 2 + half;
            const int idx = bt[p >> 4] * PBS + (p & (PBS - 1));
            const float* vp = (idx == slot_b) ? newv
                                              : (v_cache + (size_t)idx * HIDDEN + h * HD);
            v4[u] = *reinterpret_cast<const float4*>(vp + l32 * 4);
            pr[u] = sc[p];
        }
#pragma unroll
        for (int u = 0; u < 8; ++u) {
            acc[u].x += pr[u] * v4[u].x;
            acc[u].y += pr[u] * v4[u].y;
            acc[u].z += pr[u] * v4[u].z;
            acc[u].w += pr[u] * v4[u].w;
        }
    }
    float4 a = acc[0];
#pragma unroll
    for (int u = 1; u < 8; ++u) {
        a.x += acc[u].x; a.y += acc[u].y; a.z += acc[u].z; a.w += acc[u].w;
    }
    a.x += __shfl_xor(a.x, 32, 64);
    a.y += __shfl_xor(a.y, 32, 64);
    a.z += __shfl_xor(a.z, 32, 64);
    a.w += __shfl_xor(a.w, 32, 64);

    if (half == 0)
        *reinterpret_cast<float4*>(&stage[wid * HD + l32 * 4]) = a;
    __syncthreads();
    if (wid == 0) {
        float t0 = 0.f, t1 = 0.f;
        for (int w = 0; w < nw; ++w) {
            t0 += stage[w * HD + lane * 2];
            t1 += stage[w * HD + lane * 2 + 1];
        }
        float* po = part_o + ((size_t)bh * NSPLIT + split) * HD;
        po[lane * 2]     = t0;
        po[lane * 2 + 1] = t1;
        if (lane == 0) {
            part_ml[((size_t)bh * NSPLIT + split) * 2]     = bm;
            part_ml[((size_t)bh * NSPLIT + split) * 2 + 1] = tot;
        }
    }
}

// Combine NSPLIT partials per (b,h). One block per bh, HD threads.
__global__ __launch_bounds__(HD) void attn_reduce(const float* __restrict__ part_o,
                                                  const float* __restrict__ part_ml,
                                                  float* __restrict__ attn_out) {
    const int bh = blockIdx.x;
    const int d  = threadIdx.x;
    float M = -1e30f;
#pragma unroll
    for (int i = 0; i < NSPLIT; ++i)
        M = fmaxf(M, part_ml[((size_t)bh * NSPLIT + i) * 2]);
    float L = 0.f, o = 0.f;
#pragma unroll
    for (int i = 0; i < NSPLIT; ++i) {
        const float mi = part_ml[((size_t)bh * NSPLIT + i) * 2];
        const float li = part_ml[((size_t)bh * NSPLIT + i) * 2 + 1];
        const float w  = __expf(mi - M);
        L += li * w;
        o += part_o[((size_t)bh * NSPLIT + i) * HD + d] * w;
    }
    attn_out[(size_t)bh * HD + d] = o / L;
}

extern "C" void kernel_launch(void* const* d_in, const int* in_sizes, int n_in,
                              void* d_out, int out_size, void* d_ws, size_t ws_size,
                              hipStream_t stream) {
    const float* hidden  = (const float*)d_in[0];
    const float* cosb    = (const float*)d_in[1];
    const float* sinb    = (const float*)d_in[2];
    const float* w_qkv   = (const float*)d_in[3];
    const float* b_qkv   = (const float*)d_in[4];
    const float* w_o     = (const float*)d_in[5];
    const float* k_cache = (const float*)d_in[6];
    const float* v_cache = (const float*)d_in[7];
    const int*   btab    = (const int*)d_in[8];
    const int*   slots   = (const int*)d_in[9];
    const int*   lens    = (const int*)d_in[10];

    const int B = in_sizes[0] / HIDDEN;      // 8
    const int max_blocks = in_sizes[8] / B;  // 128
    const int S = max_blocks * PBS;          // 2048

    float* qkv     = (float*)d_ws;                        // [B][QKVN]
    float* attn    = qkv + (size_t)B * QKVN;              // [B][HIDDEN]
    float* part_o  = attn + (size_t)B * HIDDEN;           // [B*NH*NSPLIT][HD]
    float* part_ml = part_o + (size_t)B * NH * NSPLIT * HD;  // [B*NH*NSPLIT][2]
    float* out     = (float*)d_out;

    // 1) qkv = hidden @ w_qkv^T + b_qkv   (LDS-staged x, 16 rows/block)
    gemv_lds<4><<<QKVN / 16, 256, 0, stream>>>(hidden, w_qkv, b_qkv, qkv, QKVN, HIDDEN);

    // 2) RoPE on q and k
    {
        const int total = 2 * B * NH * (HD / 2);
        rope_k<<<(total + 255) / 256, 256, 0, stream>>>(qkv, cosb, sinb, B);
    }

    // 3) paged attention partials + reduce
    {
        const int SP = S / NSPLIT;
        const size_t smem = (size_t)(SP + SP / PBS + 16 + 4 * HD) * sizeof(float);
        attn_part<<<B * NH * NSPLIT, 256, smem, stream>>>(qkv, k_cache, v_cache,
                                                          btab, slots, lens,
                                                          part_o, part_ml, S, max_blocks);
        attn_reduce<<<B * NH, HD, 0, stream>>>(part_o, part_ml, attn);
    }

    // 4) out = attn @ w_o^T   (LDS-staged x, 8 rows/block -> 512 blocks)
    gemv_lds<2><<<HIDDEN / 8, 256, 0, stream>>>(attn, w_o, nullptr, out, HIDDEN, HIDDEN);
}

// Round 9
// 184.417 us; speedup vs baseline: 1.1783x; 1.0120x over previous
//
#include <hip/hip_runtime.h>

#define NH 32
#define HD 128
#define PBS 16
#define HIDDEN (NH * HD)   // 4096
#define QKVN (3 * HIDDEN)  // 12288
#define NSPLIT 8
#define KC 512             // k-chunk staged in LDS

// out[b][n] = dot(x[b,:K], W[n,:K]) + bias[n], B=8 fixed.
// Block = 256 thr = 4 waves; each wave owns NR rows; x staged in LDS per
// k-chunk (one x read per block, not per wave) to kill the L2 slice hotspot.
template <int NR>
__global__ __launch_bounds__(256) void gemv_lds(const float* __restrict__ x,
                                                const float* __restrict__ W,
                                                const float* __restrict__ bias,
                                                float* __restrict__ out,
                                                int N, int K) {
    __shared__ float xs[8][KC];
    const int tid  = threadIdx.x;
    const int lane = tid & 63;
    const int wid  = tid >> 6;
    const int n0   = blockIdx.x * (NR * 4) + wid * NR;
    const float* w0 = W + (size_t)n0 * K;

    float acc[NR][8];
#pragma unroll
    for (int r = 0; r < NR; ++r)
#pragma unroll
        for (int b = 0; b < 8; ++b) acc[r][b] = 0.f;

    for (int kc = 0; kc < K; kc += KC) {
        __syncthreads();  // previous chunk fully consumed
        {
            const int bq  = tid >> 5;
            const int t32 = tid & 31;
            const float* xb = x + (size_t)bq * K + kc;
#pragma unroll
            for (int j = 0; j < 4; ++j) {
                const int off = (t32 + j * 32) * 4;
                *reinterpret_cast<float4*>(&xs[bq][off]) =
                    *reinterpret_cast<const float4*>(xb + off);
            }
        }
        __syncthreads();
#pragma unroll
        for (int j = 0; j < 2; ++j) {
            const int kk = lane * 4 + j * 256;
            float4 w4[NR];
#pragma unroll
            for (int r = 0; r < NR; ++r)
                w4[r] = *reinterpret_cast<const float4*>(w0 + (size_t)r * K + kc + kk);
#pragma unroll
            for (int b = 0; b < 8; ++b) {
                const float4 x4 = *reinterpret_cast<const float4*>(&xs[b][kk]);
#pragma unroll
                for (int r = 0; r < NR; ++r)
                    acc[r][b] += w4[r].x * x4.x + w4[r].y * x4.y +
                                 w4[r].z * x4.z + w4[r].w * x4.w;
            }
        }
    }
#pragma unroll
    for (int r = 0; r < NR; ++r)
#pragma unroll
        for (int b = 0; b < 8; ++b)
#pragma unroll
            for (int off = 32; off > 0; off >>= 1)
                acc[r][b] += __shfl_xor(acc[r][b], off, 64);
    if (lane == 0) {
#pragma unroll
        for (int r = 0; r < NR; ++r) {
            const float bv = bias ? bias[n0 + r] : 0.f;
#pragma unroll
            for (int b = 0; b < 8; ++b)
                out[(size_t)b * N + n0 + r] = acc[r][b] + bv;
        }
    }
}

// In-place RoPE on q and k halves of qkv ws. One thread per (part,b,h,d<64).
__global__ __launch_bounds__(256) void rope_k(float* __restrict__ qkv,
                                              const float* __restrict__ cosb,
                                              const float* __restrict__ sinb,
                                              int B) {
    const int tid = blockIdx.x * blockDim.x + threadIdx.x;
    const int total = 2 * B * NH * (HD / 2);
    if (tid >= total) return;
    const int d = tid % (HD / 2);
    const int h = (tid / (HD / 2)) % NH;
    const int b = (tid / (HD / 2) / NH) % B;
    const int part = tid / (HD / 2) / NH / B;  // 0=q, 1=k
    const float c = cosb[b * (HD / 2) + d];
    const float s = sinb[b * (HD / 2) + d];
    float* p = qkv + (size_t)b * QKVN + part * HIDDEN + h * HD + d;
    const float x1 = p[0];
    const float x2 = p[HD / 2];
    p[0]      = x1 * c - x2 * s;
    p[HD / 2] = x1 * s + x2 * c;
}

// One-pass online-softmax partial: one block per (b,h,split), 256 thr = 4
// waves. Per page (16 tokens): 8 K-loads + 8 V-loads in flight, scores stay
// in registers (every lane holds its half's score after the xor reduce),
// flash-style (m,l,acc) update. No LDS score buffer, no mid-loop barriers.
__global__ __launch_bounds__(256) void attn_part(const float* __restrict__ qkv,
                                                 const float* __restrict__ k_cache,
                                                 const float* __restrict__ v_cache,
                                                 const int* __restrict__ block_tables,
                                                 const int* __restrict__ slots,
                                                 const int* __restrict__ lengths,
                                                 float* __restrict__ part_o,
                                                 float* __restrict__ part_ml,
                                                 int S, int max_blocks) {
    const int split = blockIdx.x % NSPLIT;
    const int bh    = blockIdx.x / NSPLIT;
    const int b     = bh >> 5;
    const int h     = bh & 31;
    const int SP    = S / NSPLIT;       // 256
    const int base  = split * SP;

    __shared__ int   bt[64];            // SP/PBS = 16 used
    __shared__ float stage[4][HD + 2];

    const int tid  = threadIdx.x;
    const int lane = tid & 63;
    const int wid  = tid >> 6;
    const int nw   = 4;
    const int half = lane >> 5;
    const int l32  = lane & 31;

    const int nbt = SP / PBS;  // 16
    for (int i = tid; i < nbt; i += blockDim.x)
        bt[i] = block_tables[b * max_blocks + base / PBS + i];
    __syncthreads();

    const int slot_b = slots[b];
    const int len    = lengths[b];
    const float scale = 0.088388347648318447f;  // 1/sqrt(128)

    const float* qp   = qkv + (size_t)b * QKVN + h * HD;
    const float* newk = qp + HIDDEN;
    const float* newv = qp + 2 * HIDDEN;
    const float4 q4 = *reinterpret_cast<const float4*>(qp + l32 * 4);

    float m = -1e30f, l = 0.f;
    float4 acc[8];
#pragma unroll
    for (int u = 0; u < 8; ++u) acc[u] = make_float4(0.f, 0.f, 0.f, 0.f);

    const int STEP = nw * 16;  // 64
    for (int s0 = wid * 16; s0 < SP; s0 += STEP) {
        float4 k4[8], v4[8];
#pragma unroll
        for (int u = 0; u < 8; ++u) {
            const int p = s0 + u * 2 + half;
            const int idx = bt[p >> 4] * PBS + (p & (PBS - 1));
            const float* kp = (idx == slot_b) ? newk
                                              : (k_cache + (size_t)idx * HIDDEN + h * HD);
            k4[u] = *reinterpret_cast<const float4*>(kp + l32 * 4);
            const float* vp = (idx == slot_b) ? newv
                                              : (v_cache + (size_t)idx * HIDDEN + h * HD);
            v4[u] = *reinterpret_cast<const float4*>(vp + l32 * 4);
        }
        float sc[8];
#pragma unroll
        for (int u = 0; u < 8; ++u) {
            float d = k4[u].x * q4.x + k4[u].y * q4.y + k4[u].z * q4.z + k4[u].w * q4.w;
#pragma unroll
            for (int off = 16; off > 0; off >>= 1) d += __shfl_xor(d, off, 64);
            const int p = s0 + u * 2 + half;
            sc[u] = (base + p < len) ? d * scale : -1e30f;
        }
        float pm = sc[0];
#pragma unroll
        for (int u = 1; u < 8; ++u) pm = fmaxf(pm, sc[u]);
        const float mn = fmaxf(m, pm);
        const float r = __expf(m - mn);
        m = mn;
        l *= r;
        float pu[8];
#pragma unroll
        for (int u = 0; u < 8; ++u) {
            pu[u] = __expf(sc[u] - mn);
            l += pu[u];
        }
#pragma unroll
        for (int u = 0; u < 8; ++u) {
            acc[u].x = fmaf(pu[u], v4[u].x, acc[u].x * r);
            acc[u].y = fmaf(pu[u], v4[u].y, acc[u].y * r);
            acc[u].z = fmaf(pu[u], v4[u].z, acc[u].z * r);
            acc[u].w = fmaf(pu[u], v4[u].w, acc[u].w * r);
        }
    }
    // sum the 8 accumulators (all share current m)
    float4 a = acc[0];
#pragma unroll
    for (int u = 1; u < 8; ++u) {
        a.x += acc[u].x; a.y += acc[u].y; a.z += acc[u].z; a.w += acc[u].w;
    }
    // merge the two halves (even/odd tokens): (m,l,o) flash merge via xor 32
    {
        const float m2 = __shfl_xor(m, 32, 64);
        const float l2 = __shfl_xor(l, 32, 64);
        float4 a2;
        a2.x = __shfl_xor(a.x, 32, 64);
        a2.y = __shfl_xor(a.y, 32, 64);
        a2.z = __shfl_xor(a.z, 32, 64);
        a2.w = __shfl_xor(a.w, 32, 64);
        const float M  = fmaxf(m, m2);
        const float e1 = __expf(m - M);
        const float e2 = __expf(m2 - M);
        l = l * e1 + l2 * e2;
        a.x = a.x * e1 + a2.x * e2;
        a.y = a.y * e1 + a2.y * e2;
        a.z = a.z * e1 + a2.z * e2;
        a.w = a.w * e1 + a2.w * e2;
        m = M;
    }
    // cross-wave merge via LDS
    if (half == 0) {
        *reinterpret_cast<float4*>(&stage[wid][l32 * 4]) = a;
        if (l32 == 0) { stage[wid][HD] = m; stage[wid][HD + 1] = l; }
    }
    __syncthreads();
    if (wid == 0) {
        float M4 = stage[0][HD];
#pragma unroll
        for (int w = 1; w < 4; ++w) M4 = fmaxf(M4, stage[w][HD]);
        float L = 0.f, t0 = 0.f, t1 = 0.f;
#pragma unroll
        for (int w = 0; w < 4; ++w) {
            const float e = __expf(stage[w][HD] - M4);
            L  += stage[w][HD + 1] * e;
            t0 += stage[w][lane * 2] * e;
            t1 += stage[w][lane * 2 + 1] * e;
        }
        float* po = part_o + ((size_t)bh * NSPLIT + split) * HD;
        po[lane * 2]     = t0;
        po[lane * 2 + 1] = t1;
        if (lane == 0) {
            part_ml[((size_t)bh * NSPLIT + split) * 2]     = M4;
            part_ml[((size_t)bh * NSPLIT + split) * 2 + 1] = L;
        }
    }
}

// Combine NSPLIT partials per (b,h). One block per bh, HD threads.
__global__ __launch_bounds__(HD) void attn_reduce(const float* __restrict__ part_o,
                                                  const float* __restrict__ part_ml,
                                                  float* __restrict__ attn_out) {
    const int bh = blockIdx.x;
    const int d  = threadIdx.x;
    float M = -1e30f;
#pragma unroll
    for (int i = 0; i < NSPLIT; ++i)
        M = fmaxf(M, part_ml[((size_t)bh * NSPLIT + i) * 2]);
    float L = 0.f, o = 0.f;
#pragma unroll
    for (int i = 0; i < NSPLIT; ++i) {
        const float mi = part_ml[((size_t)bh * NSPLIT + i) * 2];
        const float li = part_ml[((size_t)bh * NSPLIT + i) * 2 + 1];
        const float w  = __expf(mi - M);
        L += li * w;
        o += part_o[((size_t)bh * NSPLIT + i) * HD + d] * w;
    }
    attn_out[(size_t)bh * HD + d] = o / L;
}

extern "C" void kernel_launch(void* const* d_in, const int* in_sizes, int n_in,
                              void* d_out, int out_size, void* d_ws, size_t ws_size,
                              hipStream_t stream) {
    const float* hidden  = (const float*)d_in[0];
    const float* cosb    = (const float*)d_in[1];
    const float* sinb    = (const float*)d_in[2];
    const float* w_qkv   = (const float*)d_in[3];
    const float* b_qkv   = (const float*)d_in[4];
    const float* w_o     = (const float*)d_in[5];
    const float* k_cache = (const float*)d_in[6];
    const float* v_cache = (const float*)d_in[7];
    const int*   btab    = (const int*)d_in[8];
    const int*   slots   = (const int*)d_in[9];
    const int*   lens    = (const int*)d_in[10];

    const int B = in_sizes[0] / HIDDEN;      // 8
    const int max_blocks = in_sizes[8] / B;  // 128
    const int S = max_blocks * PBS;          // 2048

    float* qkv     = (float*)d_ws;                        // [B][QKVN]
    float* attn    = qkv + (size_t)B * QKVN;              // [B][HIDDEN]
    float* part_o  = attn + (size_t)B * HIDDEN;           // [B*NH*NSPLIT][HD]
    float* part_ml = part_o + (size_t)B * NH * NSPLIT * HD;  // [B*NH*NSPLIT][2]
    float* out     = (float*)d_out;

    // 1) qkv = hidden @ w_qkv^T + b_qkv   (LDS-staged x, 16 rows/block)
    gemv_lds<4><<<QKVN / 16, 256, 0, stream>>>(hidden, w_qkv, b_qkv, qkv, QKVN, HIDDEN);

    // 2) RoPE on q and k
    {
        const int total = 2 * B * NH * (HD / 2);
        rope_k<<<(total + 255) / 256, 256, 0, stream>>>(qkv, cosb, sinb, B);
    }

    // 3) paged attention partials (one-pass online softmax) + reduce
    attn_part<<<B * NH * NSPLIT, 256, 0, stream>>>(qkv, k_cache, v_cache,
                                                   btab, slots, lens,
                                                   part_o, part_ml, S, max_blocks);
    attn_reduce<<<B * NH, HD, 0, stream>>>(part_o, part_ml, attn);

    // 4) out = attn @ w_o^T   (LDS-staged x, 8 rows/block -> 512 blocks)
    gemv_lds<2><<<HIDDEN / 8, 256, 0, stream>>>(attn, w_o, nullptr, out, HIDDEN, HIDDEN);
}